// Round 9
// baseline (111.668 us; speedup 1.0000x reference)
//
#include <hip/hip_runtime.h>
#include <math.h>

#define EPSV 1e-12f

// ---------- Kernel 1: partial column sums, contiguous row-chunk blocks ----------
// grid = C blocks. Block c owns rows [c*rpc, c*rpc+rpc_eff) (contiguous 256 KB).
// Thread t accumulates float4-cols t, t+256, t+512, t+768. partial[c][D].
__global__ __launch_bounds__(256)
void ara_colsum(const float* __restrict__ hid, float* __restrict__ partial,
                int D4, int S, int rows_per_chunk) {
    const int tid = threadIdx.x;
    const int c = blockIdx.x;
    const float4* h4 = reinterpret_cast<const float4*>(hid);
    float4* p4 = reinterpret_cast<float4*>(partial);
    long row0 = (long)c * rows_per_chunk;
    int rpc_eff = rows_per_chunk;
    if (row0 + rpc_eff > S) rpc_eff = (int)(S - row0);
    const float4* base = h4 + row0 * (long)D4;
    const int G = D4 >> 8;               // col groups of 256 float4

    if (G == 4) {                        // fast path (D = 4096)
        float4 a0 = make_float4(0.f,0.f,0.f,0.f), a1 = a0, a2 = a0, a3 = a0;
        for (int r = 0; r < rpc_eff; ++r) {
            const float4* row = base + (long)r * D4;
            float4 v0 = row[tid];
            float4 v1 = row[tid + 256];
            float4 v2 = row[tid + 512];
            float4 v3 = row[tid + 768];
            a0.x += v0.x; a0.y += v0.y; a0.z += v0.z; a0.w += v0.w;
            a1.x += v1.x; a1.y += v1.y; a1.z += v1.z; a1.w += v1.w;
            a2.x += v2.x; a2.y += v2.y; a2.z += v2.z; a2.w += v2.w;
            a3.x += v3.x; a3.y += v3.y; a3.z += v3.z; a3.w += v3.w;
        }
        float4* dst = p4 + (long)c * D4;
        dst[tid]       = a0;
        dst[tid + 256] = a1;
        dst[tid + 512] = a2;
        dst[tid + 768] = a3;
    } else {
        for (int g = 0; g < G; ++g) {
            float4 acc = make_float4(0.f,0.f,0.f,0.f);
            int col = (g << 8) + tid;
            for (int r = 0; r < rpc_eff; ++r) {
                float4 v = base[(long)r * D4 + col];
                acc.x += v.x; acc.y += v.y; acc.z += v.z; acc.w += v.w;
            }
            p4[(long)c * D4 + col] = acc;
        }
    }
}

// ---------- Kernel 2: reduce partials + 6 dot products ----------
__global__ __launch_bounds__(256)
void ara_reduce(const float* __restrict__ partial, const float* __restrict__ cdir,
                const float* __restrict__ idir, float* __restrict__ ws6,
                int D4, int C) {
    const float4* p4 = reinterpret_cast<const float4*>(partial);
    const float4* c4p = reinterpret_cast<const float4*>(cdir);
    const float4* i4p = reinterpret_cast<const float4*>(idir);
    int lane = threadIdx.x & 63;
    int g = threadIdx.x >> 6;                 // 0..3
    int col = blockIdx.x * 64 + lane;
    bool valid = col < D4;
    int per = (C + 3) / 4;
    float4 acc = make_float4(0.f, 0.f, 0.f, 0.f);
    if (valid) {
        for (int j = 0; j < per; ++j) {
            int c = g * per + j;
            if (c < C) {
                float4 v = p4[(long)c * D4 + col];
                acc.x += v.x; acc.y += v.y; acc.z += v.z; acc.w += v.w;
            }
        }
    }
    __shared__ float4 lds[4][64];
    lds[g][lane] = acc;
    __syncthreads();
    if (threadIdx.x < 64) {
        float vals[6] = {0.f, 0.f, 0.f, 0.f, 0.f, 0.f};
        if (valid) {
            float4 s;
            s.x = lds[0][lane].x + lds[1][lane].x + lds[2][lane].x + lds[3][lane].x;
            s.y = lds[0][lane].y + lds[1][lane].y + lds[2][lane].y + lds[3][lane].y;
            s.z = lds[0][lane].z + lds[1][lane].z + lds[2][lane].z + lds[3][lane].z;
            s.w = lds[0][lane].w + lds[1][lane].w + lds[2][lane].w + lds[3][lane].w;
            float4 c = c4p[col], iv = i4p[col];
            vals[0] = c.x*c.x + c.y*c.y + c.z*c.z + c.w*c.w;
            vals[1] = iv.x*iv.x + iv.y*iv.y + iv.z*iv.z + iv.w*iv.w;
            vals[2] = s.x*c.x + s.y*c.y + s.z*c.z + s.w*c.w;
            vals[3] = s.x*iv.x + s.y*iv.y + s.z*iv.z + s.w*iv.w;
            vals[4] = s.x*s.x + s.y*s.y + s.z*s.z + s.w*s.w;
            float dx = c.x-iv.x, dy = c.y-iv.y, dz = c.z-iv.z, dw = c.w-iv.w;
            vals[5] = dx*dx + dy*dy + dz*dz + dw*dw;
        }
#pragma unroll
        for (int k = 0; k < 6; ++k) {
            float v = vals[k];
#pragma unroll
            for (int o = 32; o > 0; o >>= 1) v += __shfl_down(v, o, 64);
            if (lane == 0) ws6[blockIdx.x * 6 + k] = v;
        }
    }
}

// ---------- Kernel 3: apply ----------
// grid = S/rows_per_block x 256, rows_per_block=4 contiguous rows. Per row:
// issue all 4 hidden loads, then compute + 4 stores (max MLP).
__global__ __launch_bounds__(256)
void ara_apply(const float* __restrict__ hid, const float* __restrict__ cdir,
               const float* __restrict__ idir, const float* __restrict__ sscale,
               const float* __restrict__ ws6, float* __restrict__ out,
               int D4, int S, int NB, int rows_per_block) {
    __shared__ float sv[256];
    __shared__ float bc[3];
    int tid = threadIdx.x;
    int n6 = NB * 6;
    if (tid < n6 && tid < 256) sv[tid] = ws6[tid];
    __syncthreads();
    if (tid == 0) {
        float t[6] = {0.f, 0.f, 0.f, 0.f, 0.f, 0.f};
        for (int b = 0; b < NB; ++b)
#pragma unroll
            for (int k = 0; k < 6; ++k) t[k] += sv[b * 6 + k];
        float invS = 1.0f / (float)S;
        float cn = sqrtf(t[4]) * invS;                  // ||mean||
        float inv_cn = 1.0f / fmaxf(cn, EPSV);
        float csim = (sqrtf(t[0]) > 0.f) ? (t[2] * invS * inv_cn) : 0.f;
        float isim = (sqrtf(t[1]) > 0.f) ? (t[3] * invS * inv_cn) : 0.f;
        float quality = csim - isim;
        float amp = 0.5f * (0.1f - quality) / (0.1f + 0.3f);
        float alpha = (quality < -0.3f) ? 0.5f : ((quality < 0.1f) ? amp : 0.05f);
        float ndiff = sqrtf(t[5]);
        float inv_nd = 1.0f / fmaxf(ndiff, EPSV);
        bc[0] = alpha * sscale[0];
        bc[1] = inv_nd;
        bc[2] = ndiff * inv_nd;                         // ||momentum||
    }
    __syncthreads();
    const float a_s = bc[0], inv_nd = bc[1], mnorm = bc[2];
    const float invS = 1.0f / (float)S;

    const float4* h4 = reinterpret_cast<const float4*>(hid);
    const float4* c4p = reinterpret_cast<const float4*>(cdir);
    const float4* i4p = reinterpret_cast<const float4*>(idir);
    float4* o4 = reinterpret_cast<float4*>(out);

    const int G = D4 >> 8;
    long row0 = (long)blockIdx.x * rows_per_block;

    if (G == 4) {                                       // fast path (D = 4096)
        float4 m0, m1, m2, m3;
        {
            float4 c0 = c4p[tid],       i0 = i4p[tid];
            float4 c1 = c4p[tid + 256], i1 = i4p[tid + 256];
            float4 c2 = c4p[tid + 512], i2 = i4p[tid + 512];
            float4 c3 = c4p[tid + 768], i3 = i4p[tid + 768];
            m0.x = (c0.x - i0.x) * inv_nd; m0.y = (c0.y - i0.y) * inv_nd;
            m0.z = (c0.z - i0.z) * inv_nd; m0.w = (c0.w - i0.w) * inv_nd;
            m1.x = (c1.x - i1.x) * inv_nd; m1.y = (c1.y - i1.y) * inv_nd;
            m1.z = (c1.z - i1.z) * inv_nd; m1.w = (c1.w - i1.w) * inv_nd;
            m2.x = (c2.x - i2.x) * inv_nd; m2.y = (c2.y - i2.y) * inv_nd;
            m2.z = (c2.z - i2.z) * inv_nd; m2.w = (c2.w - i2.w) * inv_nd;
            m3.x = (c3.x - i3.x) * inv_nd; m3.y = (c3.y - i3.y) * inv_nd;
            m3.z = (c3.z - i3.z) * inv_nd; m3.w = (c3.w - i3.w) * inv_nd;
        }
        for (int r = 0; r < rows_per_block; ++r) {
            long s = row0 + r;
            if (s >= S) break;
            float eff = a_s * (0.5f + 0.5f * ((float)s * invS));
            float dn = fabsf(eff) * mnorm;
            float coef = (dn > 0.5f) ? (eff * (0.5f / dn)) : eff;
            const float4* row = h4 + s * (long)D4;
            float4* orow = o4 + s * (long)D4;
            float4 h0 = row[tid];
            float4 h1 = row[tid + 256];
            float4 h2 = row[tid + 512];
            float4 h3 = row[tid + 768];
            float4 r0, r1, r2, r3;
            r0.x = h0.x + coef * m0.x; r0.y = h0.y + coef * m0.y;
            r0.z = h0.z + coef * m0.z; r0.w = h0.w + coef * m0.w;
            r1.x = h1.x + coef * m1.x; r1.y = h1.y + coef * m1.y;
            r1.z = h1.z + coef * m1.z; r1.w = h1.w + coef * m1.w;
            r2.x = h2.x + coef * m2.x; r2.y = h2.y + coef * m2.y;
            r2.z = h2.z + coef * m2.z; r2.w = h2.w + coef * m2.w;
            r3.x = h3.x + coef * m3.x; r3.y = h3.y + coef * m3.y;
            r3.z = h3.z + coef * m3.z; r3.w = h3.w + coef * m3.w;
            orow[tid]       = r0;
            orow[tid + 256] = r1;
            orow[tid + 512] = r2;
            orow[tid + 768] = r3;
        }
    } else {                                            // generic path
        for (int r = 0; r < rows_per_block; ++r) {
            long s = row0 + r;
            if (s >= S) break;
            float eff = a_s * (0.5f + 0.5f * ((float)s * invS));
            float dn = fabsf(eff) * mnorm;
            float coef = (dn > 0.5f) ? (eff * (0.5f / dn)) : eff;
            for (int g = 0; g < G; ++g) {
                int col = (g << 8) + tid;
                long idx = s * (long)D4 + col;
                float4 c = c4p[col], iv = i4p[col];
                float4 h = h4[idx];
                float4 rr;
                rr.x = h.x + coef * (c.x - iv.x) * inv_nd;
                rr.y = h.y + coef * (c.y - iv.y) * inv_nd;
                rr.z = h.z + coef * (c.z - iv.z) * inv_nd;
                rr.w = h.w + coef * (c.w - iv.w) * inv_nd;
                o4[idx] = rr;
            }
        }
    }
}

extern "C" void kernel_launch(void* const* d_in, const int* in_sizes, int n_in,
                              void* d_out, int out_size, void* d_ws, size_t ws_size,
                              hipStream_t stream) {
    const float* hid    = (const float*)d_in[0];
    const float* cdir   = (const float*)d_in[1];
    const float* idir   = (const float*)d_in[2];
    const float* sscale = (const float*)d_in[3];
    float* out = (float*)d_out;

    int D = in_sizes[1];                 // 4096
    long total = (long)in_sizes[0];      // B*S*D, B=1
    int S = (int)(total / D);            // 8192
    int D4 = D / 4;

    const int C = 512;                   // row chunks (512 blocks, 16 rows each)
    int rows_per_chunk = (S + C - 1) / C;

    float* partial = (float*)d_ws;                       // C*D floats (8 MB)
    float* ws6 = partial + (size_t)C * D;                // NB*6 floats

    ara_colsum<<<C, 256, 0, stream>>>(hid, partial, D4, S, rows_per_chunk);

    int NB = (D4 + 63) / 64;             // 16 for D=4096
    ara_reduce<<<NB, 256, 0, stream>>>(partial, cdir, idir, ws6, D4, C);

    int rows_per_block = 4;
    int g3 = (S + rows_per_block - 1) / rows_per_block;  // 2048
    ara_apply<<<g3, 256, 0, stream>>>(hid, cdir, idir, sscale, ws6, out,
                                      D4, S, NB, rows_per_block);
}